// Round 1
// baseline (598.294 us; speedup 1.0000x reference)
//
#include <hip/hip_runtime.h>

// PGWCrossAttention on MI355X (gfx950), bf16 MFMA pipeline.
// Dims fixed by the problem:
#define Bsz 8
#define Nq  2048
#define Mk  2048
#define DINv 512
#define Hd  256
#define RQ  (Bsz*Nq)    // 16384 query rows
#define RK  (Bsz*Mk)    // 16384 key rows
#define BKt 32          // K-tile per MFMA step

typedef __attribute__((ext_vector_type(8))) short   short8;   // 8 bf16 (4 VGPRs)
typedef __attribute__((ext_vector_type(4))) float   floatx4;  // MFMA acc

__device__ __forceinline__ unsigned short f2bf(float f) {
  union { float f; unsigned u; } x; x.f = f;
  unsigned r = x.u + 0x7fffu + ((x.u >> 16) & 1u);   // RNE
  return (unsigned short)(r >> 16);
}
__device__ __forceinline__ float bf2f(unsigned short s) {
  union { unsigned u; float f; } x; x.u = ((unsigned)s) << 16;
  return x.f;
}

// ---------------------------------------------------------------------------
// NT GEMM core: C(128x128) += A[128 rows, K] . B[128 rows, K]^T, bf16 in LDS,
// fp32 acc. 256 threads = 4 waves (2x2), each wave 4x4 tiles of 16x16.
// A/B fragment layout (m89/m91-verified): elem[m=lane&15][k=(lane>>4)*8+j].
// C/D layout: col=lane&15, row=(lane>>4)*4+reg.
// ---------------------------------------------------------------------------
__device__ __forceinline__ void gemm_core_nt(
    const unsigned short* __restrict__ A, int lda,
    const unsigned short* __restrict__ B, int ldb,
    int K, unsigned short* ldsA, unsigned short* ldsB,
    floatx4 (&acc)[4][4])
{
  const int tid  = threadIdx.x;
  const int lane = tid & 63;
  const int sr   = tid >> 2;          // staging row 0..63
  const int sc   = (tid & 3) << 3;    // staging col 0/8/16/24
  const int wid  = tid >> 6;
  const int wm   = wid & 1;
  const int wn   = wid >> 1;
  const int fr   = lane & 15;
  const int fk   = (lane >> 4) << 3;

  const unsigned short* a0p = A + (size_t)sr * lda + sc;
  const unsigned short* a1p = A + (size_t)(sr + 64) * lda + sc;
  const unsigned short* b0p = B + (size_t)sr * ldb + sc;
  const unsigned short* b1p = B + (size_t)(sr + 64) * ldb + sc;
  uint4* sa0 = (uint4*)(ldsA + sr * BKt + sc);
  uint4* sa1 = (uint4*)(ldsA + (sr + 64) * BKt + sc);
  uint4* sb0 = (uint4*)(ldsB + sr * BKt + sc);
  uint4* sb1 = (uint4*)(ldsB + (sr + 64) * BKt + sc);
  const unsigned short* fa = ldsA + (wm * 64 + fr) * BKt + fk;
  const unsigned short* fb = ldsB + (wn * 64 + fr) * BKt + fk;

  for (int k0 = 0; k0 < K; k0 += BKt) {
    uint4 a0 = *(const uint4*)a0p; a0p += BKt;
    uint4 a1 = *(const uint4*)a1p; a1p += BKt;
    uint4 b0 = *(const uint4*)b0p; b0p += BKt;
    uint4 b1 = *(const uint4*)b1p; b1p += BKt;
    __syncthreads();                  // protect prior iter's frag reads
    *sa0 = a0; *sa1 = a1; *sb0 = b0; *sb1 = b1;
    __syncthreads();
    short8 af[4], bf[4];
#pragma unroll
    for (int i = 0; i < 4; i++) af[i] = *(const short8*)(fa + i * 16 * BKt);
#pragma unroll
    for (int i = 0; i < 4; i++) bf[i] = *(const short8*)(fb + i * 16 * BKt);
#pragma unroll
    for (int i = 0; i < 4; i++)
#pragma unroll
      for (int j = 0; j < 4; j++)
        acc[i][j] = __builtin_amdgcn_mfma_f32_16x16x32_bf16(af[i], bf[j], acc[i][j], 0, 0, 0);
  }
}

#define EPILOGUE_VARS \
  const int lane = threadIdx.x & 63; \
  const int wid  = threadIdx.x >> 6; \
  const int wm   = wid & 1; \
  const int wn   = wid >> 1; \
  const int r4   = (lane >> 4) * 4;  \
  const int cn   = lane & 15;

// ---------------------------------------------------------------------------
// Generic bias-GEMM. MODE 0: store bf16. MODE 1: silu -> bf16. MODE 2: fp32.
// ---------------------------------------------------------------------------
template<int MODE>
__global__ __launch_bounds__(256) void k_gemm_bias(
    const unsigned short* __restrict__ A, const unsigned short* __restrict__ Bw,
    const float* __restrict__ bias, void* __restrict__ Cout, int Ncols, int K)
{
  __shared__ alignas(16) unsigned short ldsA[128 * BKt];
  __shared__ alignas(16) unsigned short ldsB[128 * BKt];
  floatx4 acc[4][4];
#pragma unroll
  for (int i = 0; i < 4; i++)
#pragma unroll
    for (int j = 0; j < 4; j++)
#pragma unroll
      for (int t = 0; t < 4; t++) acc[i][j][t] = 0.f;

  const unsigned short* Ab = A + (size_t)blockIdx.x * 128 * K;
  const unsigned short* Bb = Bw + (size_t)blockIdx.y * 128 * K;
  gemm_core_nt(Ab, K, Bb, K, K, ldsA, ldsB, acc);

  EPILOGUE_VARS
#pragma unroll
  for (int i = 0; i < 4; i++) {
#pragma unroll
    for (int j = 0; j < 4; j++) {
      int gc = blockIdx.y * 128 + wn * 64 + j * 16 + cn;
      float bv = bias[gc];
#pragma unroll
      for (int r = 0; r < 4; r++) {
        int gr = blockIdx.x * 128 + wm * 64 + i * 16 + r4 + r;
        float v = acc[i][j][r] + bv;
        if constexpr (MODE == 1) v = v / (1.f + __expf(-v));
        if constexpr (MODE == 2)
          ((float*)Cout)[(size_t)gr * Ncols + gc] = v;
        else
          ((unsigned short*)Cout)[(size_t)gr * Ncols + gc] = f2bf(v);
      }
    }
  }
}

// ---------------------------------------------------------------------------
// Pass 1: sum of electronic distances -> dsum[b] (for electronic_scale).
// ---------------------------------------------------------------------------
__global__ __launch_bounds__(256) void k_pass1(
    const unsigned short* __restrict__ Xq, const unsigned short* __restrict__ Xk,
    const float* __restrict__ q2, const float* __restrict__ k2, float* __restrict__ dsum)
{
  __shared__ alignas(16) unsigned short ldsA[128 * BKt];
  __shared__ alignas(16) unsigned short ldsB[128 * BKt];
  floatx4 acc[4][4];
#pragma unroll
  for (int i = 0; i < 4; i++)
#pragma unroll
    for (int j = 0; j < 4; j++)
#pragma unroll
      for (int t = 0; t < 4; t++) acc[i][j][t] = 0.f;

  const int b = blockIdx.z;
  const unsigned short* Ab = Xq + ((size_t)(b * Nq) + blockIdx.x * 128) * 512 + 256;   // q_elec
  const unsigned short* Bb = Xk + ((size_t)(b * Mk) + blockIdx.y * 128) * 1024 + 512;  // k_elec
  gemm_core_nt(Ab, 512, Bb, 1024, 256, ldsA, ldsB, acc);

  EPILOGUE_VARS
  const int rowBase = b * Nq + blockIdx.x * 128;
  const int colBase = b * Mk + blockIdx.y * 128;
  float lsum = 0.f;
#pragma unroll
  for (int i = 0; i < 4; i++) {
#pragma unroll
    for (int j = 0; j < 4; j++) {
      float kk = k2[colBase + wn * 64 + j * 16 + cn];
#pragma unroll
      for (int r = 0; r < 4; r++) {
        float qq = q2[rowBase + wm * 64 + i * 16 + r4 + r];
        float d2 = qq + kk - 2.f * acc[i][j][r];
        lsum += sqrtf(fmaxf(d2, 1e-12f));
      }
    }
  }
#pragma unroll
  for (int o = 32; o; o >>= 1) lsum += __shfl_down(lsum, o);
  __syncthreads();
  float* red = (float*)ldsA;
  if (lane == 0) red[wid] = lsum;
  __syncthreads();
  if (threadIdx.x == 0) atomicAdd(dsum + b, red[0] + red[1] + red[2] + red[3]);
}

// ---------------------------------------------------------------------------
// Logits: struct-dot/16 - ew*d/scale + gamma*log(max(pi,1e-9)) -> f16 S.
// ---------------------------------------------------------------------------
__global__ __launch_bounds__(256) void k_logits(
    const unsigned short* __restrict__ Xq, const unsigned short* __restrict__ Xk,
    const float* __restrict__ q2, const float* __restrict__ k2,
    const float* __restrict__ dsum, const float* __restrict__ pi,
    const float* __restrict__ gamma_p, const float* __restrict__ ew_p,
    _Float16* __restrict__ S)
{
  __shared__ alignas(16) unsigned short ldsA[128 * BKt];
  __shared__ alignas(16) unsigned short ldsB[128 * BKt];
  floatx4 accS[4][4], accE[4][4];
#pragma unroll
  for (int i = 0; i < 4; i++)
#pragma unroll
    for (int j = 0; j < 4; j++)
#pragma unroll
      for (int t = 0; t < 4; t++) { accS[i][j][t] = 0.f; accE[i][j][t] = 0.f; }

  const int b = blockIdx.z;
  const unsigned short* Aq_s = Xq + ((size_t)(b * Nq) + blockIdx.x * 128) * 512;
  const unsigned short* Bk_s = Xk + ((size_t)(b * Mk) + blockIdx.y * 128) * 1024;
  gemm_core_nt(Aq_s,       512, Bk_s,       1024, 256, ldsA, ldsB, accS);  // struct
  gemm_core_nt(Aq_s + 256, 512, Bk_s + 512, 1024, 256, ldsA, ldsB, accE);  // elec

  const float scale = fmaxf(dsum[b] * (1.f / (2048.f * 2048.f)), 1e-4f);
  const float einv  = ew_p[0] / scale;
  const float gv    = gamma_p[0];

  EPILOGUE_VARS
#pragma unroll
  for (int i = 0; i < 4; i++) {
#pragma unroll
    for (int j = 0; j < 4; j++) {
      int m = blockIdx.y * 128 + wn * 64 + j * 16 + cn;
      float kk = k2[b * Mk + m];
#pragma unroll
      for (int r = 0; r < 4; r++) {
        int n = blockIdx.x * 128 + wm * 64 + i * 16 + r4 + r;
        float qq = q2[b * Nq + n];
        float d  = sqrtf(fmaxf(qq + kk - 2.f * accE[i][j][r], 1e-12f));
        float p  = pi[((size_t)b * Nq + n) * Mk + m];
        float l  = accS[i][j][r] * 0.0625f - einv * d + gv * __logf(fmaxf(p, 1e-9f));
        S[((size_t)b * Nq + n) * Mk + m] = (_Float16)l;
      }
    }
  }
}

// ---------------------------------------------------------------------------
// Row softmax: read f16 logits, write bf16 weights in-place (same region).
// ---------------------------------------------------------------------------
__global__ __launch_bounds__(256) void k_softmax(
    const _Float16* __restrict__ S, unsigned short* __restrict__ W)
{
  __shared__ float red[8];
  const size_t rowoff = (size_t)blockIdx.x * Mk;
  const int t = threadIdx.x;
  union { uint4 u; _Float16 h[8]; } inb;
  inb.u = *(const uint4*)(S + rowoff + t * 8);
  float f[8];
  float mx = -1e30f;
#pragma unroll
  for (int i = 0; i < 8; i++) { f[i] = (float)inb.h[i]; mx = fmaxf(mx, f[i]); }
  const int lane = t & 63, wid = t >> 6;
#pragma unroll
  for (int o = 32; o; o >>= 1) mx = fmaxf(mx, __shfl_down(mx, o));
  if (lane == 0) red[wid] = mx;
  __syncthreads();
  mx = fmaxf(fmaxf(red[0], red[1]), fmaxf(red[2], red[3]));
  float s = 0.f;
#pragma unroll
  for (int i = 0; i < 8; i++) { f[i] = __expf(f[i] - mx); s += f[i]; }
#pragma unroll
  for (int o = 32; o; o >>= 1) s += __shfl_down(s, o);
  if (lane == 0) red[4 + wid] = s;
  __syncthreads();
  s = red[4] + red[5] + red[6] + red[7];
  const float rinv = 1.f / s;
  unsigned short os[8];
#pragma unroll
  for (int i = 0; i < 8; i++) os[i] = f2bf(f[i] * rinv);
  uint4 o4;
  o4.x = os[0] | ((unsigned)os[1] << 16);
  o4.y = os[2] | ((unsigned)os[3] << 16);
  o4.z = os[4] | ((unsigned)os[5] << 16);
  o4.w = os[6] | ((unsigned)os[7] << 16);
  *(uint4*)(W + rowoff + t * 8) = o4;
}

// ---------------------------------------------------------------------------
// PV: ctx[b, n, 0:512] = attn @ [v_struct | v_elec]  (VT is [b, 512, M])
// ---------------------------------------------------------------------------
__global__ __launch_bounds__(256) void k_pv(
    const unsigned short* __restrict__ At, const unsigned short* __restrict__ VT,
    unsigned short* __restrict__ ctx)
{
  __shared__ alignas(16) unsigned short ldsA[128 * BKt];
  __shared__ alignas(16) unsigned short ldsB[128 * BKt];
  floatx4 acc[4][4];
#pragma unroll
  for (int i = 0; i < 4; i++)
#pragma unroll
    for (int j = 0; j < 4; j++)
#pragma unroll
      for (int t = 0; t < 4; t++) acc[i][j][t] = 0.f;

  const int b = blockIdx.z;
  const unsigned short* Ab = At + ((size_t)b * Nq + blockIdx.x * 128) * (size_t)Mk;
  const unsigned short* Bb = VT + ((size_t)b * 512 + blockIdx.y * 128) * (size_t)Mk;
  gemm_core_nt(Ab, Mk, Bb, Mk, Mk, ldsA, ldsB, acc);

  EPILOGUE_VARS
#pragma unroll
  for (int i = 0; i < 4; i++)
#pragma unroll
    for (int j = 0; j < 4; j++) {
      int gc = blockIdx.y * 128 + wn * 64 + j * 16 + cn;
#pragma unroll
      for (int r = 0; r < 4; r++) {
        int gr = blockIdx.x * 128 + wm * 64 + i * 16 + r4 + r;
        ctx[((size_t)b * Nq + gr) * 512 + gc] = f2bf(acc[i][j][r]);
      }
    }
}

// ---------------------------------------------------------------------------
// Small utility kernels
// ---------------------------------------------------------------------------
__global__ void k_f32_bf16(const float* __restrict__ src, unsigned short* __restrict__ dst) {
  size_t i = ((size_t)blockIdx.x * 256 + threadIdx.x) * 4;
  float4 v = *(const float4*)(src + i);
  uint2 o;
  o.x = f2bf(v.x) | ((unsigned)f2bf(v.y) << 16);
  o.y = f2bf(v.z) | ((unsigned)f2bf(v.w) << 16);
  *(uint2*)(dst + i) = o;
}

// transpose + concat weights -> bf16; concat biases; zero dsum
__global__ void k_prep_w(
    const float* __restrict__ Wqs, const float* __restrict__ Wqe,
    const float* __restrict__ Wks, const float* __restrict__ Wvs,
    const float* __restrict__ Wke, const float* __restrict__ Wve,
    const float* __restrict__ W1,  const float* __restrict__ W2,
    const float* __restrict__ bqs, const float* __restrict__ bqe,
    const float* __restrict__ bks, const float* __restrict__ bvs,
    const float* __restrict__ bke, const float* __restrict__ bve,
    unsigned short* __restrict__ WqT, unsigned short* __restrict__ WkT,
    unsigned short* __restrict__ W1T, unsigned short* __restrict__ W2T,
    float* __restrict__ bq, float* __restrict__ bk, float* __restrict__ dsum)
{
  int gid = blockIdx.x * 256 + threadIdx.x;
  int idx = gid;
  if (idx < 512 * 512) {                       // WqT[j,k], j: qs|qe
    int j = idx >> 9, k = idx & 511;
    float v = (j < 256) ? Wqs[k * 256 + j] : Wqe[k * 256 + (j - 256)];
    WqT[idx] = f2bf(v);
  } else if ((idx -= 512 * 512) < 1024 * 512) { // WkT[j,k], j: ks|vs|ke|ve
    int j = idx >> 9, k = idx & 511;
    int s = j >> 8, jj = j & 255;
    const float* Wp = (s == 0) ? Wks : (s == 1) ? Wvs : (s == 2) ? Wke : Wve;
    WkT[idx] = f2bf(Wp[k * 256 + jj]);
  } else if ((idx -= 1024 * 512) < 256 * 1024) { // W1T[j,k]
    int j = idx >> 10, k = idx & 1023;
    W1T[idx] = f2bf(W1[k * 256 + j]);
  } else if ((idx -= 256 * 1024) < 256 * 256) {  // W2T[j,k]
    int j = idx >> 8, k = idx & 255;
    W2T[idx] = f2bf(W2[k * 256 + j]);
  }
  if (gid < 512)  bq[gid] = (gid < 256) ? bqs[gid] : bqe[gid - 256];
  if (gid < 1024) bk[gid] = (gid < 256) ? bks[gid]
                    : (gid < 512) ? bvs[gid - 256]
                    : (gid < 768) ? bke[gid - 512] : bve[gid - 768];
  if (gid < 8) dsum[gid] = 0.f;
}

// row sum-of-squares over 256 bf16 columns (one wave per row)
__global__ __launch_bounds__(256) void k_rowsq(
    const unsigned short* __restrict__ X, int stride, int colOff, float* __restrict__ out)
{
  int row = blockIdx.x * 4 + (threadIdx.x >> 6);
  int lane = threadIdx.x & 63;
  const unsigned short* p = X + (size_t)row * stride + colOff + lane * 4;
  uint2 u = *(const uint2*)p;
  float a0 = bf2f((unsigned short)(u.x & 0xffff));
  float a1 = bf2f((unsigned short)(u.x >> 16));
  float a2 = bf2f((unsigned short)(u.y & 0xffff));
  float a3 = bf2f((unsigned short)(u.y >> 16));
  float s = a0 * a0 + a1 * a1 + a2 * a2 + a3 * a3;
#pragma unroll
  for (int o = 32; o; o >>= 1) s += __shfl_down(s, o);
  if (lane == 0) out[row] = s;
}

// VT[b, j, m] = Xk[b*M+m, (j<256)?256+j:512+j]  (v_struct | v_elec transposed)
__global__ void k_trans_vt(const unsigned short* __restrict__ Xk, unsigned short* __restrict__ VT) {
  __shared__ unsigned short t[32][33];
  const int b = blockIdx.z;
  const int m0 = blockIdx.x * 32, j0 = blockIdx.y * 32;
  const int tx = threadIdx.x, ty = threadIdx.y;
#pragma unroll
  for (int i = 0; i < 4; i++) {
    int m = m0 + ty + i * 8;
    int j = j0 + tx;
    int c = (j < 256) ? (256 + j) : (512 + j);
    t[ty + i * 8][tx] = Xk[((size_t)b * Mk + m) * 1024 + c];
  }
  __syncthreads();
#pragma unroll
  for (int i = 0; i < 4; i++) {
    int j = j0 + ty + i * 8;
    int m = m0 + tx;
    VT[((size_t)b * 512 + j) * Mk + m] = t[tx][ty + i * 8];
  }
}

// fused = [ctx_s | ctx_e | ctx_s-ctx_e | ctx_s*ctx_e]
__global__ void k_fused(const unsigned short* __restrict__ ctx, unsigned short* __restrict__ fused) {
  int idx = blockIdx.x * 256 + threadIdx.x;
  int bn = idx >> 8;
  int j = idx & 255;
  float cs = bf2f(ctx[(size_t)bn * 512 + j]);
  float ce = bf2f(ctx[(size_t)bn * 512 + 256 + j]);
  size_t o = (size_t)bn * 1024 + j;
  fused[o]       = f2bf(cs);
  fused[o + 256] = f2bf(ce);
  fused[o + 512] = f2bf(cs - ce);
  fused[o + 768] = f2bf(cs * ce);
}

// ---------------------------------------------------------------------------
extern "C" void kernel_launch(void* const* d_in, const int* in_sizes, int n_in,
                              void* d_out, int out_size, void* d_ws, size_t ws_size,
                              hipStream_t stream) {
  (void)in_sizes; (void)n_in; (void)out_size; (void)ws_size;
  const float* q_fp  = (const float*)d_in[0];
  const float* v_ret = (const float*)d_in[1];
  const float* pi    = (const float*)d_in[2];
  const float* Wqs = (const float*)d_in[3];  const float* bqs = (const float*)d_in[4];
  const float* Wks = (const float*)d_in[5];  const float* bks = (const float*)d_in[6];
  const float* Wvs = (const float*)d_in[7];  const float* bvs = (const float*)d_in[8];
  const float* Wqe = (const float*)d_in[9];  const float* bqe = (const float*)d_in[10];
  const float* Wke = (const float*)d_in[11]; const float* bke = (const float*)d_in[12];
  const float* Wve = (const float*)d_in[13]; const float* bve = (const float*)d_in[14];
  const float* W1  = (const float*)d_in[15]; const float* b1  = (const float*)d_in[16];
  const float* W2  = (const float*)d_in[17]; const float* b2  = (const float*)d_in[18];
  const float* gamma = (const float*)d_in[19];
  const float* ew    = (const float*)d_in[20];

  char* w = (char*)d_ws;                       // ~170.2 MB total
  unsigned short* WqT = (unsigned short*)(w + 0);          // 512x512 bf16
  unsigned short* WkT = (unsigned short*)(w + 524288);     // 1024x512
  unsigned short* W1T = (unsigned short*)(w + 1572864);    // 256x1024
  unsigned short* W2T = (unsigned short*)(w + 2097152);    // 256x256
  float* bq   = (float*)(w + 2228224);                     // 512
  float* bk   = (float*)(w + 2230272);                     // 1024
  float* q2   = (float*)(w + 2234368);                     // 16384
  float* k2   = (float*)(w + 2299904);                     // 16384
  float* dsum = (float*)(w + 2365440);                     // 8
  unsigned short* Aq = (unsigned short*)(w + 2365696);     // 16384x512 bf16
  unsigned short* Ak = (unsigned short*)(w + 19142912);    // 16384x512
  unsigned short* Xq = (unsigned short*)(w + 35920128);    // 16384x512 (qs|qe)
  unsigned short* Xk = (unsigned short*)(w + 52697344);    // 16384x1024 (ks|vs|ke|ve)
  unsigned short* VT = (unsigned short*)(w + 86251776);    // 8x512x2048
  _Float16*       S  = (_Float16*)(w + 103028992);         // 8x2048x2048 f16 logits
  unsigned short* attn = (unsigned short*)(w + 103028992); // reuse: bf16 weights
  unsigned short* ctx  = Aq;                               // reuse (Aq dead after proj)
  unsigned short* fused = (unsigned short*)(w + 103028992);// reuse S region after PV
  unsigned short* hbuf  = Ak;                              // reuse (Ak dead after proj)

  k_f32_bf16<<<8192, 256, 0, stream>>>(q_fp, Aq);
  k_f32_bf16<<<8192, 256, 0, stream>>>(v_ret, Ak);
  k_prep_w<<<4352, 256, 0, stream>>>(Wqs, Wqe, Wks, Wvs, Wke, Wve, W1, W2,
                                     bqs, bqe, bks, bvs, bke, bve,
                                     WqT, WkT, W1T, W2T, bq, bk, dsum);
  // projections: Xq = [q_struct|q_elec], Xk = [k_struct|v_struct|k_elec|v_elec]
  k_gemm_bias<0><<<dim3(128, 4), 256, 0, stream>>>(Aq, WqT, bq, Xq, 512, 512);
  k_gemm_bias<0><<<dim3(128, 8), 256, 0, stream>>>(Ak, WkT, bk, Xk, 1024, 512);
  k_rowsq<<<4096, 256, 0, stream>>>(Xq, 512, 256, q2);
  k_rowsq<<<4096, 256, 0, stream>>>(Xk, 1024, 512, k2);
  // pass 1: per-batch mean electronic distance
  k_pass1<<<dim3(16, 16, 8), 256, 0, stream>>>(Xq, Xk, q2, k2, dsum);
  // logits -> f16 S
  k_logits<<<dim3(16, 16, 8), 256, 0, stream>>>(Xq, Xk, q2, k2, dsum, pi, gamma, ew, S);
  // softmax rows -> bf16 attn (in place)
  k_softmax<<<16384, 256, 0, stream>>>(S, attn);
  // transpose v_struct/v_elec -> VT
  k_trans_vt<<<dim3(64, 16, 8), dim3(32, 8), 0, stream>>>(Xk, VT);
  // ctx = attn @ [Vs|Ve]
  k_pv<<<dim3(16, 4, 8), 256, 0, stream>>>(attn, VT, ctx);
  // fused features
  k_fused<<<16384, 256, 0, stream>>>(ctx, fused);
  // MLP: h = silu(fused @ W1 + b1); out = h @ W2 + b2 (fp32)
  k_gemm_bias<1><<<dim3(128, 2), 256, 0, stream>>>(fused, W1T, b1, hbuf, 256, 1024);
  k_gemm_bias<2><<<dim3(128, 2), 256, 0, stream>>>(hbuf, W2T, b2, d_out, 256, 256);
}